// Round 12
// baseline (581.909 us; speedup 1.0000x reference)
//
#include <hip/hip_runtime.h>
#include <hip/hip_fp16.h>

// BN scale constant: 1/sqrt(1+1e-5)
#define RSQ_BN 0.9999950000374997f

typedef _Float16 f16x8 __attribute__((ext_vector_type(8)));
typedef float f32x4 __attribute__((ext_vector_type(4)));

union H8u { uint4 u4; __half h[8]; };
union H4u { uint2 u2; __half h[4]; };

__device__ __forceinline__ float leaky02(float x) { return x > 0.f ? x : 0.2f * x; }

__device__ __forceinline__ float4 ld4(const float* p) {
    return *reinterpret_cast<const float4*>(p);
}
__device__ __forceinline__ void ld8(float* d, const float* p) {
    float4 u = ld4(p), v = ld4(p + 4);
    d[0] = u.x; d[1] = u.y; d[2] = u.z; d[3] = u.w;
    d[4] = v.x; d[5] = v.y; d[6] = v.z; d[7] = v.w;
}

// ---------------- CSR build ----------------

__global__ void hist_k(const int* __restrict__ edst, int* __restrict__ cnt, int E, int EN) {
    int i = blockIdx.x * 256 + threadIdx.x;
    if (i >= EN) return;
    int d = (i < E) ? edst[i] : (i - E);   // self-loop for i>=E
    atomicAdd(&cnt[d], 1);
}

// single-launch decoupled-lookback scan: rowptr/cursor/dis in one kernel.
// Block b publishes its inclusive prefix in gpart[b] and sets gflag[b];
// it spins on gflag[b-1]. All 118 blocks are co-resident -> no deadlock.
__global__ __launch_bounds__(256)
void scan_dl_k(const int* __restrict__ cnt, int* __restrict__ rowptr,
               int* __restrict__ cursor, float* __restrict__ dis,
               int* __restrict__ gflag, int* __restrict__ gpart,
               int n, int EN) {
    __shared__ int sh[256];
    __shared__ int sbase;
    int t = threadIdx.x;
    int b = blockIdx.x;
    int i = b * 256 + t;
    int v = (i < n) ? cnt[i] : 0;
    sh[t] = v;
    __syncthreads();
#pragma unroll
    for (int off = 1; off < 256; off <<= 1) {
        int u = (t >= off) ? sh[t - off] : 0;
        __syncthreads();
        sh[t] += u;
        __syncthreads();
    }
    if (t == 0) {
        int total = sh[255];
        int prev = 0;
        if (b > 0) {
            while (atomicAdd(&gflag[b - 1], 0) == 0) { }
            prev = atomicAdd(&gpart[b - 1], 0);
        }
        gpart[b] = prev + total;
        __threadfence();
        atomicExch(&gflag[b], 1);
        sbase = prev;
    }
    __syncthreads();
    int base = sbase;
    if (i < n) {
        int r = base + sh[t] - v;   // exclusive prefix
        rowptr[i] = r;
        cursor[i] = r;
        dis[i] = rsqrtf((float)v);
    }
    if (i == 0) rowptr[n] = EN;
}

__global__ void scatter_k(const int* __restrict__ esrc, const int* __restrict__ edst,
                          int* __restrict__ cursor, int* __restrict__ colidx, int E, int EN) {
    int i = blockIdx.x * 256 + threadIdx.x;
    if (i >= EN) return;
    int s, d;
    if (i < E) { s = esrc[i]; d = edst[i]; }
    else       { s = i - E; d = s; }
    int pos = atomicAdd(&cursor[d], 1);
    colidx[pos] = s;
}

// ---------------- all-weights -> MFMA-fragment-order fp16 (one launch) ----------------
// Fragment order: off(ct,k32,lane,j) = ((ct*(K/32)+k32)*64 + lane)*8 + j, where
// lane=quad*16+m holds element (k = k32*32+quad*8+j, col = ct*16+m).
// Also computes the layer-0 algebraic folds:
//   Mg0 = gcn_in_w @ gcn_w[0]   (64x128, K=64 frags)  cg0 = gcn_in_b @ gcn_w[0]
//   Ma0 = gat_in_w @ gat_w[0]   (64x128)              ca0 = gat_in_b @ gat_w[0]
//   Da  = gat_in_w @ PD0        (64x16 tile)          oa  = gat_in_b @ PD0
// where PD0 is layer-0's projected attention tile (asrc cols 0..3, adst cols 8..11).

__device__ __forceinline__ float pd0_elem(const float* __restrict__ gat_w,
                                          const float* __restrict__ gat_asrc,
                                          const float* __restrict__ gat_adst,
                                          int t, int col) {
    // layer 0: hh=4, C=32
    float p = 0.f;
    if (col < 4) {
        const float* w = gat_w + (size_t)t * 128 + col * 32;
        const float* av = gat_asrc + col * 32;
        for (int c2 = 0; c2 < 32; ++c2) p += w[c2] * av[c2];
    } else if (col >= 8 && col < 12) {
        int hh2 = col - 8;
        const float* w = gat_w + (size_t)t * 128 + hh2 * 32;
        const float* av = gat_adst + hh2 * 32;
        for (int c2 = 0; c2 < 32; ++c2) p += w[c2] * av[c2];
    }
    return p;
}

__global__ void wtx_all_k(const float* __restrict__ gcn_in_w, const float* __restrict__ gcn_res_w,
                          const float* __restrict__ gat_in_w,
                          const float* __restrict__ gcn_w, const float* __restrict__ gat_w,
                          const float* __restrict__ gcn_c1w, const float* __restrict__ gat_c1w,
                          const float* __restrict__ gcn_c3w, const float* __restrict__ gat_c3w,
                          const float* __restrict__ fin_w,
                          const float* __restrict__ gcn_c2w, const float* __restrict__ gat_c2w,
                          const float* __restrict__ gat_asrc, const float* __restrict__ gat_adst,
                          const float* __restrict__ gcn_in_b, const float* __restrict__ gat_in_b,
                          __half* __restrict__ WTin, __half* __restrict__ WTg,
                          __half* __restrict__ WTa, __half* __restrict__ WTc1,
                          __half* __restrict__ WTc3, __half* __restrict__ WTfin,
                          __half* __restrict__ WTc2, __half* __restrict__ WTd,
                          __half* __restrict__ Mg0, __half* __restrict__ Ma0,
                          __half* __restrict__ Da, float* __restrict__ cg0,
                          float* __restrict__ ca0, float* __restrict__ oa) {
    int idx = blockIdx.x * 256 + threadIdx.x;
    const float* src;
    __half* dst;
    int K, M, o;
    if (idx < 24576) {                      // 3x (64x128) input mats
        int mi = idx >> 13; o = idx & 8191;
        src = mi == 0 ? gcn_in_w : (mi == 1 ? gcn_res_w : gat_in_w);
        dst = WTin + mi * 8192; K = 64; M = 128;
    } else if (idx < 73728) {               // 3x (128x128) gcn layer mats
        int r = idx - 24576; int mi = r >> 14; o = r & 16383;
        src = gcn_w + mi * 16384; dst = WTg + mi * 16384; K = 128; M = 128;
    } else if (idx < 122880) {              // 3x (128x128) gat layer mats
        int r = idx - 73728; int mi = r >> 14; o = r & 16383;
        src = gat_w + mi * 16384; dst = WTa + mi * 16384; K = 128; M = 128;
    } else if (idx < 139264) {              // 2x (128x64) c1 mats
        int r = idx - 122880; int mi = r >> 13; o = r & 8191;
        src = mi ? gat_c1w : gcn_c1w; dst = WTc1 + mi * 8192; K = 128; M = 64;
    } else if (idx < 147456) {              // 2x (32x128) c3 mats
        int r = idx - 139264; int mi = r >> 12; o = r & 4095;
        src = mi ? gat_c3w : gcn_c3w; dst = WTc3 + mi * 4096; K = 32; M = 128;
    } else if (idx < 155648) {              // fin (128x64)
        o = idx - 147456; src = fin_w; dst = WTfin; K = 128; M = 64;
    } else if (idx < 159744) {              // 2x (64x32) c2 mats
        int r = idx - 155648; int mi = r >> 11; o = r & 2047;
        src = mi ? gat_c2w : gcn_c2w; dst = WTc2 + mi * 2048; K = 64; M = 32;
    } else if (idx < 165888) {              // 3x (16x128) projected attention tiles
        int r = idx - 159744;
        int layer = r >> 11; o = r & 2047;
        int j = o & 7, lane = (o >> 3) & 63, k32 = o >> 9;
        int col = lane & 15, quad = lane >> 4;
        int k = k32 * 32 + quad * 8 + j;
        int hh = (layer < 2) ? 4 : 1;
        int C = 128 / hh;
        float v = 0.f;
        if (col < hh) {
            const float* w = gat_w + (size_t)(layer * 128 + k) * 128 + col * C;
            const float* av = gat_asrc + layer * 128 + col * C;
            for (int c2 = 0; c2 < C; ++c2) v += w[c2] * av[c2];
        } else if (col >= 8 && col < 8 + hh) {
            int hthis = col - 8;
            const float* w = gat_w + (size_t)(layer * 128 + k) * 128 + hthis * C;
            const float* av = gat_adst + layer * 128 + hthis * C;
            for (int c2 = 0; c2 < C; ++c2) v += w[c2] * av[c2];
        }
        WTd[(size_t)layer * 2048 + o] = (__half)v;
        return;
    } else if (idx < 183296) {              // Mg0 / Ma0 folded layer-0 mats (K=64 frags)
        int r = idx - 165888;
        bool isA = r >= 8192;
        o = r & 8191;
        int j = o & 7, lane = (o >> 3) & 63, rr = o >> 9;
        int ct = rr >> 1, k32 = rr & 1;
        int m = lane & 15, quad = lane >> 4;
        int k = k32 * 32 + quad * 8 + j;
        int col = ct * 16 + m;
        const float* inw = isA ? gat_in_w : gcn_in_w;
        const float* lw  = isA ? gat_w : gcn_w;   // layer 0
        float v = 0.f;
        for (int t = 0; t < 128; ++t) v += inw[k * 128 + t] * lw[(size_t)t * 128 + col];
        (isA ? Ma0 : Mg0)[o] = (__half)v;
        return;
    } else if (idx < 184320) {              // Da = gat_in_w @ PD0 (64x16 tile, K=64 frags)
        o = idx - 183296;
        int j = o & 7, lane = (o >> 3) & 63, k32 = o >> 9;
        int col = lane & 15, quad = lane >> 4;
        int k = k32 * 32 + quad * 8 + j;
        float v = 0.f;
        if (col < 4 || (col >= 8 && col < 12)) {
            for (int t = 0; t < 128; ++t)
                v += gat_in_w[k * 128 + t] * pd0_elem(gat_w, gat_asrc, gat_adst, t, col);
        }
        Da[o] = (__half)v;
        return;
    } else if (idx < 184448) {              // cg0 = gcn_in_b @ gcn_w0
        int col = idx - 184320;
        float v = 0.f;
        for (int t = 0; t < 128; ++t) v += gcn_in_b[t] * gcn_w[(size_t)t * 128 + col];
        cg0[col] = v;
        return;
    } else if (idx < 184576) {              // ca0 = gat_in_b @ gat_w0
        int col = idx - 184448;
        float v = 0.f;
        for (int t = 0; t < 128; ++t) v += gat_in_b[t] * gat_w[(size_t)t * 128 + col];
        ca0[col] = v;
        return;
    } else if (idx < 184592) {              // oa = gat_in_b @ PD0 (16 tile cols)
        int col = idx - 184576;
        float v = 0.f;
        if (col < 4 || (col >= 8 && col < 12)) {
            for (int t = 0; t < 128; ++t)
                v += gat_in_b[t] * pd0_elem(gat_w, gat_asrc, gat_adst, t, col);
        }
        oa[col] = v;
        return;
    } else return;
    // fragment-order decomposition
    int j = o & 7, lane = (o >> 3) & 63, r = o >> 9;
    int KD32 = K >> 5;
    int ct = r / KD32, k32 = r - ct * KD32;
    int m = lane & 15, quad = lane >> 4;
    int k = k32 * 32 + quad * 8 + j;
    int mcol = ct * 16 + m;
    dst[o] = (__half)src[k * M + mcol];
}

// ---------------- MFMA dense kernels ----------------

__device__ __forceinline__ f16x8 mk_af(const float* xr, int kb) {
    float4 v0 = ld4(xr + kb), v1 = ld4(xr + kb + 4);
    f16x8 af;
    af[0] = (_Float16)v0.x; af[1] = (_Float16)v0.y;
    af[2] = (_Float16)v0.z; af[3] = (_Float16)v0.w;
    af[4] = (_Float16)v1.x; af[5] = (_Float16)v1.y;
    af[6] = (_Float16)v1.z; af[7] = (_Float16)v1.w;
    return af;
}

// ---------------- layer-0 fused dual GEMM (x fp32 in, K=64 folded weights) ----------------
// gcn blocks: Y = (x@Mg0 + cg0)*dis, plus R = x@res_w + res_b.
// gat blocks: Y = x@Ma0 + ca0, attention dots via Da tile (+oa offsets).

__global__ __launch_bounds__(256)
void dual0_mfma_k(const float* __restrict__ X,
                  const __half* __restrict__ Mg0, const __half* __restrict__ Wres,
                  const float* __restrict__ resb,
                  const __half* __restrict__ Ma0, const __half* __restrict__ Da,
                  const float* __restrict__ cg0, const float* __restrict__ ca0,
                  const float* __restrict__ oa,
                  const float* __restrict__ dis,
                  __half* __restrict__ Yg, __half* __restrict__ Rout,
                  __half* __restrict__ Ya,
                  float* __restrict__ avp, float* __restrict__ bvp,
                  int hh, int n, int gper) {
    bool gat = blockIdx.x >= gper;
    int blk = gat ? blockIdx.x - gper : blockIdx.x;
    int wave = threadIdx.x >> 6, lane = threadIdx.x & 63;
    int m = lane & 15, quad = lane >> 4;
    int row0 = blk * 64 + wave * 16;
    int arow = min(row0 + m, n - 1);
    const float* xr = X + (size_t)arow * 64;
    f16x8 xf0 = mk_af(xr, quad * 8);
    f16x8 xf1 = mk_af(xr, 32 + quad * 8);
    int row = row0 + m;
    f32x4 acc[8];
    if (!gat) {
        // ---- Y0 ----
#pragma unroll
        for (int ct = 0; ct < 8; ++ct) acc[ct] = (f32x4){0.f, 0.f, 0.f, 0.f};
#pragma unroll
        for (int ct = 0; ct < 8; ++ct) {
            f16x8 b0 = *reinterpret_cast<const f16x8*>(Mg0 + ((ct * 2 + 0) << 9) + (lane << 3));
            f16x8 b1 = *reinterpret_cast<const f16x8*>(Mg0 + ((ct * 2 + 1) << 9) + (lane << 3));
            acc[ct] = __builtin_amdgcn_mfma_f32_16x16x32_f16(b0, xf0, acc[ct], 0, 0, 0);
            acc[ct] = __builtin_amdgcn_mfma_f32_16x16x32_f16(b1, xf1, acc[ct], 0, 0, 0);
        }
        if (row < n) {
            float dv = dis[row];
#pragma unroll
            for (int ct = 0; ct < 8; ++ct) {
                int col = ct * 16 + quad * 4;
                float4 cb = ld4(cg0 + col);
                H4u w;
                w.h[0] = (__half)((acc[ct][0] + cb.x) * dv);
                w.h[1] = (__half)((acc[ct][1] + cb.y) * dv);
                w.h[2] = (__half)((acc[ct][2] + cb.z) * dv);
                w.h[3] = (__half)((acc[ct][3] + cb.w) * dv);
                *reinterpret_cast<uint2*>(Yg + (size_t)row * 128 + col) = w.u2;
            }
        }
        // ---- R ----
#pragma unroll
        for (int ct = 0; ct < 8; ++ct) acc[ct] = (f32x4){0.f, 0.f, 0.f, 0.f};
#pragma unroll
        for (int ct = 0; ct < 8; ++ct) {
            f16x8 b0 = *reinterpret_cast<const f16x8*>(Wres + ((ct * 2 + 0) << 9) + (lane << 3));
            f16x8 b1 = *reinterpret_cast<const f16x8*>(Wres + ((ct * 2 + 1) << 9) + (lane << 3));
            acc[ct] = __builtin_amdgcn_mfma_f32_16x16x32_f16(b0, xf0, acc[ct], 0, 0, 0);
            acc[ct] = __builtin_amdgcn_mfma_f32_16x16x32_f16(b1, xf1, acc[ct], 0, 0, 0);
        }
        if (row < n) {
#pragma unroll
            for (int ct = 0; ct < 8; ++ct) {
                int col = ct * 16 + quad * 4;
                float4 cb = ld4(resb + col);
                H4u w;
                w.h[0] = (__half)(acc[ct][0] + cb.x);
                w.h[1] = (__half)(acc[ct][1] + cb.y);
                w.h[2] = (__half)(acc[ct][2] + cb.z);
                w.h[3] = (__half)(acc[ct][3] + cb.w);
                *reinterpret_cast<uint2*>(Rout + (size_t)row * 128 + col) = w.u2;
            }
        }
    } else {
        f32x4 accd = (f32x4){0.f, 0.f, 0.f, 0.f};
#pragma unroll
        for (int ct = 0; ct < 8; ++ct) acc[ct] = (f32x4){0.f, 0.f, 0.f, 0.f};
#pragma unroll
        for (int ct = 0; ct < 8; ++ct) {
            f16x8 b0 = *reinterpret_cast<const f16x8*>(Ma0 + ((ct * 2 + 0) << 9) + (lane << 3));
            f16x8 b1 = *reinterpret_cast<const f16x8*>(Ma0 + ((ct * 2 + 1) << 9) + (lane << 3));
            acc[ct] = __builtin_amdgcn_mfma_f32_16x16x32_f16(b0, xf0, acc[ct], 0, 0, 0);
            acc[ct] = __builtin_amdgcn_mfma_f32_16x16x32_f16(b1, xf1, acc[ct], 0, 0, 0);
        }
        {
            f16x8 d0 = *reinterpret_cast<const f16x8*>(Da + (0 << 9) + (lane << 3));
            f16x8 d1 = *reinterpret_cast<const f16x8*>(Da + (1 << 9) + (lane << 3));
            accd = __builtin_amdgcn_mfma_f32_16x16x32_f16(d0, xf0, accd, 0, 0, 0);
            accd = __builtin_amdgcn_mfma_f32_16x16x32_f16(d1, xf1, accd, 0, 0, 0);
        }
        if (row < n) {
#pragma unroll
            for (int ct = 0; ct < 8; ++ct) {
                int col = ct * 16 + quad * 4;
                float4 cb = ld4(ca0 + col);
                H4u w;
                w.h[0] = (__half)(acc[ct][0] + cb.x);
                w.h[1] = (__half)(acc[ct][1] + cb.y);
                w.h[2] = (__half)(acc[ct][2] + cb.z);
                w.h[3] = (__half)(acc[ct][3] + cb.w);
                *reinterpret_cast<uint2*>(Ya + (size_t)row * 128 + col) = w.u2;
            }
            if (quad == 0) {
#pragma unroll
                for (int reg = 0; reg < 4; ++reg)
                    if (reg < hh) avp[row * hh + reg] = accd[reg] + oa[reg];
            } else if (quad == 2) {
#pragma unroll
                for (int reg = 0; reg < 4; ++reg)
                    if (reg < hh) bvp[row * hh + reg] = accd[reg] + oa[8 + reg];
            }
        }
    }
}

// ---------------- per-layer pair GEMM via MFMA (fp16 act, fragment weights) ----------------
// gcn blocks: Y = (X@W)*dis. gat blocks: Y = X@W + attention dots via 9th tile.

__global__ __launch_bounds__(256)
void dual128_mfma_k(const __half* __restrict__ Xg, const __half* __restrict__ WTg,
                    __half* __restrict__ Yg,
                    const __half* __restrict__ Xa, const __half* __restrict__ WTa,
                    __half* __restrict__ Ya,
                    const float* __restrict__ dis,
                    const __half* __restrict__ WTd,
                    float* __restrict__ avp, float* __restrict__ bvp,
                    int hh, int n, int gper) {
    bool gat = blockIdx.x >= gper;
    int blk = gat ? blockIdx.x - gper : blockIdx.x;
    const __half* X = gat ? Xa : Xg;
    const __half* WT = gat ? WTa : WTg;
    __half* Y = gat ? Ya : Yg;
    int wave = threadIdx.x >> 6;
    int lane = threadIdx.x & 63;
    int m = lane & 15, quad = lane >> 4;
    int row0 = blk * 64 + wave * 16;
    int arow = min(row0 + m, n - 1);
    const __half* xr = X + (size_t)arow * 128;
    f32x4 acc[8];
#pragma unroll
    for (int ct = 0; ct < 8; ++ct) acc[ct] = (f32x4){0.f, 0.f, 0.f, 0.f};
    int row = row0 + m;
    if (!gat) {
#pragma unroll
        for (int k32 = 0; k32 < 4; ++k32) {
            int kb = k32 * 32 + quad * 8;
            f16x8 af = *reinterpret_cast<const f16x8*>(xr + kb);
#pragma unroll
            for (int ct = 0; ct < 8; ++ct) {
                f16x8 bf = *reinterpret_cast<const f16x8*>(WT + ((ct * 4 + k32) << 9) + (lane << 3));
                acc[ct] = __builtin_amdgcn_mfma_f32_16x16x32_f16(bf, af, acc[ct], 0, 0, 0);
            }
        }
        if (row < n) {
            float dv = dis[row];
#pragma unroll
            for (int ct = 0; ct < 8; ++ct) {
                int col = ct * 16 + quad * 4;
                H4u w;
                w.h[0] = (__half)(acc[ct][0] * dv);
                w.h[1] = (__half)(acc[ct][1] * dv);
                w.h[2] = (__half)(acc[ct][2] * dv);
                w.h[3] = (__half)(acc[ct][3] * dv);
                *reinterpret_cast<uint2*>(Y + (size_t)row * 128 + col) = w.u2;
            }
        }
    } else {
        f32x4 accd = (f32x4){0.f, 0.f, 0.f, 0.f};
#pragma unroll
        for (int k32 = 0; k32 < 4; ++k32) {
            int kb = k32 * 32 + quad * 8;
            f16x8 af = *reinterpret_cast<const f16x8*>(xr + kb);
#pragma unroll
            for (int ct = 0; ct < 8; ++ct) {
                f16x8 bf = *reinterpret_cast<const f16x8*>(WT + ((ct * 4 + k32) << 9) + (lane << 3));
                acc[ct] = __builtin_amdgcn_mfma_f32_16x16x32_f16(bf, af, acc[ct], 0, 0, 0);
            }
            f16x8 bd = *reinterpret_cast<const f16x8*>(WTd + (k32 << 9) + (lane << 3));
            accd = __builtin_amdgcn_mfma_f32_16x16x32_f16(bd, af, accd, 0, 0, 0);
        }
        if (row < n) {
#pragma unroll
            for (int ct = 0; ct < 8; ++ct) {
                int col = ct * 16 + quad * 4;
                H4u w;
                w.h[0] = (__half)acc[ct][0];
                w.h[1] = (__half)acc[ct][1];
                w.h[2] = (__half)acc[ct][2];
                w.h[3] = (__half)acc[ct][3];
                *reinterpret_cast<uint2*>(Y + (size_t)row * 128 + col) = w.u2;
            }
            if (quad == 0) {
#pragma unroll
                for (int reg = 0; reg < 4; ++reg)
                    if (reg < hh) avp[row * hh + reg] = accd[reg];
            } else if (quad == 2) {
#pragma unroll
                for (int reg = 0; reg < 4; ++reg)
                    if (reg < hh) bvp[row * hh + reg] = accd[reg];
            }
        }
    }
}

// ---------------- fused sparse aggregation (R5/R7 structure, proven 52us) ----------------
// 16 lanes/node, 8 cols (16B fp16) per lane per table; colidx + avp software-
// pipelined; ALL edges via fully-masked 4-edge groups (no serial remainder).

__global__ __launch_bounds__(256)
void fused_gather_k(const int* __restrict__ rowptr, const int* __restrict__ colidx,
                    const float* __restrict__ dis,
                    const __half* __restrict__ Tg, const float* __restrict__ gbias,
                    const float* __restrict__ gbng, const float* __restrict__ gbnb,
                    const __half* __restrict__ res, __half* __restrict__ Yg,
                    const __half* __restrict__ Ta, const float* __restrict__ avp,
                    const float* __restrict__ bvp, const float* __restrict__ abias,
                    const float* __restrict__ abng, const float* __restrict__ abnb,
                    const float* __restrict__ fimp, __half* __restrict__ Ya,
                    int n, int hh, int log2C) {
    int idx = blockIdx.x * 256 + threadIdx.x;
    int i = idx >> 4;
    if (i >= n) return;
    int c = (idx & 15) * 8;
    int h = c >> log2C;
    float ad = bvp[i * hh + h];
    int p0 = rowptr[i], p1 = rowptr[i + 1];
    float g[8], a[8];
#pragma unroll
    for (int t = 0; t < 8; ++t) { g[t] = 0.f; a[t] = 0.f; }
    float m = -3.0e38f, s = 0.f;

    int ng = (p1 - p0 + 3) >> 2;            // fully-masked 4-edge groups
    int p = p0;
    int sx[4]; float av[4], vm[4];
#pragma unroll
    for (int j = 0; j < 4; ++j) {
        int q = p0 + j;
        vm[j] = (q < p1) ? 1.f : 0.f;
        sx[j] = colidx[min(q, p1 - 1)];
    }
#pragma unroll
    for (int j = 0; j < 4; ++j) av[j] = avp[sx[j] * hh + h];

    for (int gi = 0; gi < ng; ++gi) {
        // issue the 8 long-latency gathers first
        uint4 qg[4], qa[4];
#pragma unroll
        for (int j = 0; j < 4; ++j)
            qg[j] = *reinterpret_cast<const uint4*>(Tg + (size_t)sx[j] * 128 + c);
#pragma unroll
        for (int j = 0; j < 4; ++j)
            qa[j] = *reinterpret_cast<const uint4*>(Ta + (size_t)sx[j] * 128 + c);
        // prefetch next group's indices + attention scores while gathers fly
        int pn = p + 4;
        int sn[4]; float avn[4], vmn[4];
#pragma unroll
        for (int j = 0; j < 4; ++j) {
            int q = pn + j;
            vmn[j] = (q < p1) ? 1.f : 0.f;
            sn[j] = colidx[min(max(q, p0), p1 - 1)];
        }
#pragma unroll
        for (int j = 0; j < 4; ++j) avn[j] = avp[sn[j] * hh + h];
        // softmax scalars (v_exp_f32); invalid slots -> e=-3e38 -> w=0
        float e0 = vm[0] > 0.f ? leaky02(av[0] + ad) : -3.0e38f;
        float e1 = vm[1] > 0.f ? leaky02(av[1] + ad) : -3.0e38f;
        float e2 = vm[2] > 0.f ? leaky02(av[2] + ad) : -3.0e38f;
        float e3 = vm[3] > 0.f ? leaky02(av[3] + ad) : -3.0e38f;
        float mc = fmaxf(fmaxf(e0, e1), fmaxf(e2, e3));
        float mn = fmaxf(m, mc);
        float scale = __expf(m - mn);
        float w0 = __expf(e0 - mn), w1 = __expf(e1 - mn);
        float w2 = __expf(e2 - mn), w3 = __expf(e3 - mn);
        s = s * scale + (w0 + w1 + w2 + w3);
        m = mn;
        // GCN accumulate, masked by vm (v_fma_mix)
        {
            H8u k0, k1, k2, k3;
            k0.u4 = qg[0]; k1.u4 = qg[1]; k2.u4 = qg[2]; k3.u4 = qg[3];
#pragma unroll
            for (int t = 0; t < 8; ++t) {
                float v = g[t];
                v = fmaf(__half2float(k0.h[t]), vm[0], v);
                v = fmaf(__half2float(k1.h[t]), vm[1], v);
                v = fmaf(__half2float(k2.h[t]), vm[2], v);
                v = fmaf(__half2float(k3.h[t]), vm[3], v);
                g[t] = v;
            }
        }
        // GAT online accumulate
        {
            H8u k0, k1, k2, k3;
            k0.u4 = qa[0]; k1.u4 = qa[1]; k2.u4 = qa[2]; k3.u4 = qa[3];
#pragma unroll
            for (int t = 0; t < 8; ++t) {
                float v = a[t] * scale;
                v = fmaf(__half2float(k0.h[t]), w0, v);
                v = fmaf(__half2float(k1.h[t]), w1, v);
                v = fmaf(__half2float(k2.h[t]), w2, v);
                v = fmaf(__half2float(k3.h[t]), w3, v);
                a[t] = v;
            }
        }
        p = pn;
#pragma unroll
        for (int j = 0; j < 4; ++j) { sx[j] = sn[j]; av[j] = avn[j]; vm[j] = vmn[j]; }
    }

    // ---- GCN epilogue (fp16 out) ----
    {
        float di = dis[i];
        float bb[8], gg[8], nb[8];
        ld8(bb, gbias + c); ld8(gg, gbng + c); ld8(nb, gbnb + c);
        float o[8];
#pragma unroll
        for (int t = 0; t < 8; ++t) {
            float v = g[t] * di + bb[t];
            o[t] = fmaxf(v * (gg[t] * RSQ_BN) + nb[t], 0.f);
        }
        if (res) {
            H8u rr;
            rr.u4 = *reinterpret_cast<const uint4*>(res + (size_t)i * 128 + c);
#pragma unroll
            for (int t = 0; t < 8; ++t) o[t] += __half2float(rr.h[t]);
        }
        H8u w;
#pragma unroll
        for (int t = 0; t < 8; ++t) w.h[t] = (__half)o[t];
        *reinterpret_cast<uint4*>(Yg + (size_t)i * 128 + c) = w.u4;
    }
    // ---- GAT epilogue (fp16 out) ----
    {
        float si = 1.f / (s + 1e-16f);
        float bb[8], gg[8], nb[8];
        ld8(bb, abias + c); ld8(gg, abng + c); ld8(nb, abnb + c);
        float o[8];
#pragma unroll
        for (int t = 0; t < 8; ++t) {
            float v = a[t] * si + bb[t];
            v = v * (gg[t] * RSQ_BN) + nb[t];
            o[t] = v > 0.f ? v : expm1f(v);
        }
        if (fimp) {
            float ff[8]; ld8(ff, fimp + c);
#pragma unroll
            for (int t = 0; t < 8; ++t) o[t] *= ff[t];
        }
        H8u w;
#pragma unroll
        for (int t = 0; t < 8; ++t) w.h[t] = (__half)o[t];
        *reinterpret_cast<uint4*>(Ya + (size_t)i * 128 + c) = w.u4;
    }
}

// ---------------- fused MLP tail: c1 -> c2 -> c3 -> blend -> fin -> bn -> fin2 ----------------
// One block = 64 rows, 4 waves x 16 rows. Intermediates in LDS; fragment weights.

__global__ __launch_bounds__(256)
void fused_tail_k(const __half* __restrict__ Xg, const __half* __restrict__ Xa,
                  const __half* __restrict__ WTc1,
                  const float* __restrict__ c1bg, const float* __restrict__ c1ba,
                  const float* __restrict__ cbng, const float* __restrict__ cbnb,
                  const __half* __restrict__ WTc2,
                  const float* __restrict__ c2bg, const float* __restrict__ c2ba,
                  const __half* __restrict__ WTc3,
                  const float* __restrict__ c3bg, const float* __restrict__ c3ba,
                  const __half* __restrict__ WTfin, const float* __restrict__ finb,
                  const float* __restrict__ fbng, const float* __restrict__ fbnb,
                  const float* __restrict__ w2, const float* __restrict__ b2,
                  float* __restrict__ out, int n) {
    __shared__ alignas(16) __half h1s[2][64][88];
    __shared__ alignas(16) __half h2s[2][64][56];
    __shared__ alignas(16) __half Fs[64][152];
    int wave = threadIdx.x >> 6, lane = threadIdx.x & 63;
    int m = lane & 15, quad = lane >> 4;
    int row0 = blockIdx.x * 64 + wave * 16;
    int lr0 = wave * 16;
    int arow = min(row0 + m, n - 1);

    // ---- S1: X @ c1 (K=128,M=64), relu [+bn for gat] -> h1 ----
#pragma unroll
    for (int br = 0; br < 2; ++br) {
        const __half* xr = (br ? Xa : Xg) + (size_t)arow * 128;
        const __half* WT = WTc1 + br * 8192;
        f32x4 acc[4];
#pragma unroll
        for (int ct = 0; ct < 4; ++ct) acc[ct] = (f32x4){0.f, 0.f, 0.f, 0.f};
#pragma unroll
        for (int k32 = 0; k32 < 4; ++k32) {
            int kb = k32 * 32 + quad * 8;
            f16x8 af = *reinterpret_cast<const f16x8*>(xr + kb);
#pragma unroll
            for (int ct = 0; ct < 4; ++ct) {
                f16x8 bf = *reinterpret_cast<const f16x8*>(WT + ((ct * 4 + k32) << 9) + (lane << 3));
                acc[ct] = __builtin_amdgcn_mfma_f32_16x16x32_f16(af, bf, acc[ct], 0, 0, 0);
            }
        }
        const float* bi = br ? c1ba : c1bg;
#pragma unroll
        for (int ct = 0; ct < 4; ++ct) {
            int col = ct * 16 + m;
            float cb = bi[col];
            float cg = br ? cbng[col] * RSQ_BN : 1.f;
            float cbb = br ? cbnb[col] : 0.f;
#pragma unroll
            for (int reg = 0; reg < 4; ++reg) {
                float v = fmaxf(acc[ct][reg] + cb, 0.f) * cg + cbb;
                h1s[br][lr0 + quad * 4 + reg][col] = (__half)v;
            }
        }
    }
    __syncthreads();
    // ---- S2: h1 @ c2 (K=64,M=32), relu -> h2 ----
#pragma unroll
    for (int br = 0; br < 2; ++br) {
        f32x4 acc[2];
        acc[0] = (f32x4){0.f, 0.f, 0.f, 0.f};
        acc[1] = (f32x4){0.f, 0.f, 0.f, 0.f};
        const __half* WT = WTc2 + br * 2048;
#pragma unroll
        for (int k32 = 0; k32 < 2; ++k32) {
            int kb = k32 * 32 + quad * 8;
            f16x8 af = *reinterpret_cast<const f16x8*>(&h1s[br][lr0 + m][kb]);
#pragma unroll
            for (int ct = 0; ct < 2; ++ct) {
                f16x8 bf = *reinterpret_cast<const f16x8*>(WT + ((ct * 2 + k32) << 9) + (lane << 3));
                acc[ct] = __builtin_amdgcn_mfma_f32_16x16x32_f16(af, bf, acc[ct], 0, 0, 0);
            }
        }
        const float* bi = br ? c2ba : c2bg;
#pragma unroll
        for (int ct = 0; ct < 2; ++ct) {
            int col = ct * 16 + m;
            float cb = bi[col];
#pragma unroll
            for (int reg = 0; reg < 4; ++reg) {
                float v = fmaxf(acc[ct][reg] + cb, 0.f);
                h2s[br][lr0 + quad * 4 + reg][col] = (__half)v;
            }
        }
    }
    __syncthreads();
    // ---- S3: h2 @ c3 (K=32,M=128), both branches, blend -> F ----
    {
        f32x4 ag[8], aa[8];
#pragma unroll
        for (int ct = 0; ct < 8; ++ct) {
            ag[ct] = (f32x4){0.f, 0.f, 0.f, 0.f};
            aa[ct] = (f32x4){0.f, 0.f, 0.f, 0.f};
        }
        int kb = quad * 8;
        f16x8 afg = *reinterpret_cast<const f16x8*>(&h2s[0][lr0 + m][kb]);
        f16x8 afa = *reinterpret_cast<const f16x8*>(&h2s[1][lr0 + m][kb]);
#pragma unroll
        for (int ct = 0; ct < 8; ++ct) {
            f16x8 bfg = *reinterpret_cast<const f16x8*>(WTc3 + (ct << 9) + (lane << 3));
            f16x8 bfa = *reinterpret_cast<const f16x8*>(WTc3 + 4096 + (ct << 9) + (lane << 3));
            ag[ct] = __builtin_amdgcn_mfma_f32_16x16x32_f16(afg, bfg, ag[ct], 0, 0, 0);
            aa[ct] = __builtin_amdgcn_mfma_f32_16x16x32_f16(afa, bfa, aa[ct], 0, 0, 0);
        }
#pragma unroll
        for (int ct = 0; ct < 8; ++ct) {
            int col = ct * 16 + m;
            float cb = 0.6f * c3bg[col] + 0.4f * c3ba[col];
#pragma unroll
            for (int reg = 0; reg < 4; ++reg) {
                float v = 0.6f * ag[ct][reg] + 0.4f * aa[ct][reg] + cb;
                Fs[lr0 + quad * 4 + reg][col] = (__half)v;
            }
        }
    }
    __syncthreads();
    // ---- S4: F @ fin (K=128,M=64), relu, bn, @fin2 -> out[n,2] ----
    {
        f32x4 acc[4];
#pragma unroll
        for (int ct = 0; ct < 4; ++ct) acc[ct] = (f32x4){0.f, 0.f, 0.f, 0.f};
#pragma unroll
        for (int k32 = 0; k32 < 4; ++k32) {
            int kb = k32 * 32 + quad * 8;
            f16x8 af = *reinterpret_cast<const f16x8*>(&Fs[lr0 + m][kb]);
#pragma unroll
            for (int ct = 0; ct < 4; ++ct) {
                f16x8 bf = *reinterpret_cast<const f16x8*>(WTfin + ((ct * 4 + k32) << 9) + (lane << 3));
                acc[ct] = __builtin_amdgcn_mfma_f32_16x16x32_f16(af, bf, acc[ct], 0, 0, 0);
            }
        }
        float p0[4] = {0.f, 0.f, 0.f, 0.f}, p1[4] = {0.f, 0.f, 0.f, 0.f};
#pragma unroll
        for (int ct = 0; ct < 4; ++ct) {
            int col = ct * 16 + m;
            float cb = finb[col];
            float cg = fbng[col] * RSQ_BN;
            float cbb = fbnb[col];
            float w20 = w2[2 * col], w21 = w2[2 * col + 1];
#pragma unroll
            for (int reg = 0; reg < 4; ++reg) {
                float v = fmaxf(acc[ct][reg] + cb, 0.f) * cg + cbb;
                p0[reg] += v * w20;
                p1[reg] += v * w21;
            }
        }
        for (int off = 1; off < 16; off <<= 1) {
#pragma unroll
            for (int reg = 0; reg < 4; ++reg) {
                p0[reg] += __shfl_xor(p0[reg], off);
                p1[reg] += __shfl_xor(p1[reg], off);
            }
        }
        if (m == 0) {
#pragma unroll
            for (int reg = 0; reg < 4; ++reg) {
                int row = row0 + quad * 4 + reg;
                if (row < n) {
                    out[row * 2] = p0[reg] + b2[0];
                    out[row * 2 + 1] = p1[reg] + b2[1];
                }
            }
        }
    }
}

// ---------------- host orchestration ----------------

static inline int cdiv(int a, int b) { return (a + b - 1) / b; }

extern "C" void kernel_launch(void* const* d_in, const int* in_sizes, int n_in,
                              void* d_out, int out_size, void* d_ws, size_t ws_size,
                              hipStream_t stream) {
    const float* x       = (const float*)d_in[0];
    const int*   ei      = (const int*)d_in[1];
    const float* gcn_in_w = (const float*)d_in[2];
    const float* gcn_in_b = (const float*)d_in[3];
    const float* gcn_res_w = (const float*)d_in[4];
    const float* gcn_res_b = (const float*)d_in[5];
    const float* gcn_w   = (const float*)d_in[6];
    const float* gcn_b   = (const float*)d_in[7];
    const float* gcn_bn_g = (const float*)d_in[8];
    const float* gcn_bn_b = (const float*)d_in[9];
    const float* gcn_c1w = (const float*)d_in[10];
    const float* gcn_c1b = (const float*)d_in[11];
    const float* gcn_c2w = (const float*)d_in[12];
    const float* gcn_c2b = (const float*)d_in[13];
    const float* gcn_c3w = (const float*)d_in[14];
    const float* gcn_c3b = (const float*)d_in[15];
    const float* gat_in_w = (const float*)d_in[16];
    const float* gat_in_b = (const float*)d_in[17];
    const float* gat_w   = (const float*)d_in[18];
    const float* gat_asrc = (const float*)d_in[19];
    const float* gat_adst = (const float*)d_in[20];
    const float* gat_b   = (const float*)d_in[21];
    const float* gat_bn_g = (const float*)d_in[22];
    const float* gat_bn_b = (const float*)d_in[23];
    const float* feat_imp = (const float*)d_in[24];
    const float* gat_c1w = (const float*)d_in[25];
    const float* gat_c1b = (const float*)d_in[26];
    const float* gat_cbn_g = (const float*)d_in[27];
    const float* gat_cbn_b = (const float*)d_in[28];
    const float* gat_c2w = (const float*)d_in[29];
    const float* gat_c2b = (const float*)d_in[30];
    const float* gat_c3w = (const float*)d_in[31];
    const float* gat_c3b = (const float*)d_in[32];
    const float* fin_w   = (const float*)d_in[33];
    const float* fin_b   = (const float*)d_in[34];
    const float* fin_bn_g = (const float*)d_in[35];
    const float* fin_bn_b = (const float*)d_in[36];
    const float* fin2_w  = (const float*)d_in[37];
    const float* fin2_b  = (const float*)d_in[38];

    const int N = in_sizes[0] / 64;
    const int E = in_sizes[1] / 2;
    const int EN = E + N;
    const int* esrc = ei;
    const int* edst = ei + E;

    // workspace carve (256B aligned)
    char* wp = (char*)d_ws;
    auto alloc = [&](size_t bytes) -> void* {
        void* p = (void*)wp;
        wp += (bytes + 255) & ~(size_t)255;
        return p;
    };
    int* cnt    = (int*)alloc((size_t)N * 4);
    int* gflag  = (int*)alloc((size_t)256 * 4);   // adjacent to cnt: one memset covers both
    int* gpart  = (int*)alloc((size_t)256 * 4);
    int* rowptr = (int*)alloc((size_t)(N + 1) * 4);
    int* cursor = (int*)alloc((size_t)N * 4);
    int* colidx = (int*)alloc((size_t)EN * 4);
    float* dis  = (float*)alloc((size_t)N * 4);
    __half* A   = (__half*)alloc((size_t)N * 128 * 2);   // gcn ping (fp16)
    __half* B   = (__half*)alloc((size_t)N * 128 * 2);   // gcn pong
    __half* G   = (__half*)alloc((size_t)N * 128 * 2);   // gat ping
    __half* H   = (__half*)alloc((size_t)N * 128 * 2);   // gat pong
    __half* R   = (__half*)alloc((size_t)N * 128 * 2);   // gcn residual
    __half* Th1 = (__half*)alloc((size_t)N * 128 * 2);   // gcn fp16 gather table
    __half* Th2 = (__half*)alloc((size_t)N * 128 * 2);   // gat fp16 gather table
    float* avv  = (float*)alloc((size_t)N * 4 * 4);
    float* bvv  = (float*)alloc((size_t)N * 4 * 4);
    __half* WTin = (__half*)alloc((size_t)3 * 8192 * 2);
    __half* WTg  = (__half*)alloc((size_t)3 * 16384 * 2);
    __half* WTa  = (__half*)alloc((size_t)3 * 16384 * 2);
    __half* WTc1 = (__half*)alloc((size_t)2 * 8192 * 2);
    __half* WTc3 = (__half*)alloc((size_t)2 * 4096 * 2);
    __half* WTfin = (__half*)alloc((size_t)8192 * 2);
    __half* WTc2 = (__half*)alloc((size_t)2 * 2048 * 2);
    __half* WTd  = (__half*)alloc((size_t)3 * 2048 * 2);
    __half* Mg0  = (__half*)alloc((size_t)8192 * 2);
    __half* Ma0  = (__half*)alloc((size_t)8192 * 2);
    __half* Da   = (__half*)alloc((size_t)1024 * 2);
    float* cg0   = (float*)alloc((size_t)128 * 4);
    float* ca0   = (float*)alloc((size_t)128 * 4);
    float* oa    = (float*)alloc((size_t)16 * 4);

    // ---- CSR build (single memset, hist, 1-launch scan, scatter) + weight prep ----
    const int nScanB = cdiv(N, 256);
    size_t cntpad = (((size_t)N * 4) + 255) & ~(size_t)255;
    hipMemsetAsync(cnt, 0, cntpad + 256 * 4, stream);   // clears cnt AND gflag
    hist_k<<<cdiv(EN, 256), 256, 0, stream>>>(edst, cnt, E, EN);
    scan_dl_k<<<nScanB, 256, 0, stream>>>(cnt, rowptr, cursor, dis, gflag, gpart, N, EN);
    scatter_k<<<cdiv(EN, 256), 256, 0, stream>>>(esrc, edst, cursor, colidx, E, EN);
    wtx_all_k<<<721, 256, 0, stream>>>(gcn_in_w, gcn_res_w, gat_in_w, gcn_w, gat_w,
                                       gcn_c1w, gat_c1w, gcn_c3w, gat_c3w, fin_w,
                                       gcn_c2w, gat_c2w, gat_asrc, gat_adst,
                                       gcn_in_b, gat_in_b,
                                       WTin, WTg, WTa, WTc1, WTc3, WTfin, WTc2, WTd,
                                       Mg0, Ma0, Da, cg0, ca0, oa);

    const int g64r = cdiv(N, 64);    // mfma kernels: 64 rows/block
    const int gG   = cdiv(N, 16);    // gather: 16 nodes/block

    // ---- layer 0: folded input+conv GEMM (also produces R) ----
    dual0_mfma_k<<<2 * g64r, 256, 0, stream>>>(x, Mg0, WTin + 8192, gcn_res_b,
                                               Ma0, Da, cg0, ca0, oa, dis,
                                               Th1, R, Th2, avv, bvv, 4, N, g64r);
    fused_gather_k<<<gG, 256, 0, stream>>>(rowptr, colidx, dis,
                                           Th1, gcn_b, gcn_bn_g, gcn_bn_b, nullptr, A,
                                           Th2, avv, bvv, gat_b, gat_bn_g, gat_bn_b,
                                           nullptr, G, N, 4, 5);
    // ---- layer 1 ----
    dual128_mfma_k<<<2 * g64r, 256, 0, stream>>>(A, WTg + 16384, Th1,
                                                 G, WTa + 16384, Th2, dis,
                                                 WTd + 2048, avv, bvv, 4, N, g64r);
    fused_gather_k<<<gG, 256, 0, stream>>>(rowptr, colidx, dis,
                                           Th1, gcn_b + 128, gcn_bn_g + 128, gcn_bn_b + 128,
                                           R, B,
                                           Th2, avv, bvv, gat_b + 128, gat_bn_g + 128,
                                           gat_bn_b + 128, nullptr, H, N, 4, 5);
    // ---- layer 2 ----
    dual128_mfma_k<<<2 * g64r, 256, 0, stream>>>(B, WTg + 32768, Th1,
                                                 H, WTa + 32768, Th2, dis,
                                                 WTd + 4096, avv, bvv, 1, N, g64r);
    fused_gather_k<<<gG, 256, 0, stream>>>(rowptr, colidx, dis,
                                           Th1, gcn_b + 256, gcn_bn_g + 256, gcn_bn_b + 256,
                                           nullptr, A,
                                           Th2, avv, bvv, gat_b + 256, gat_bn_g + 256,
                                           gat_bn_b + 256, feat_imp, G, N, 1, 7);

    // ---- fused MLP tail: c1/c2/c3/blend/fin/fin2 in one kernel ----
    fused_tail_k<<<g64r, 256, 0, stream>>>(A, G,
                                           WTc1, gcn_c1b, gat_c1b, gat_cbn_g, gat_cbn_b,
                                           WTc2, gcn_c2b, gat_c2b,
                                           WTc3, gcn_c3b, gat_c3b,
                                           WTfin, fin_b, fin_bn_g, fin_bn_b,
                                           fin2_w, fin2_b, (float*)d_out, N);
}

// Round 13
// 434.543 us; speedup vs baseline: 1.3391x; 1.3391x over previous
//
#include <hip/hip_runtime.h>
#include <hip/hip_fp16.h>

// BN scale constant: 1/sqrt(1+1e-5)
#define RSQ_BN 0.9999950000374997f

typedef _Float16 f16x8 __attribute__((ext_vector_type(8)));
typedef float f32x4 __attribute__((ext_vector_type(4)));

union H8u { uint4 u4; __half h[8]; };
union H4u { uint2 u2; __half h[4]; };

__device__ __forceinline__ float leaky02(float x) { return x > 0.f ? x : 0.2f * x; }

__device__ __forceinline__ float4 ld4(const float* p) {
    return *reinterpret_cast<const float4*>(p);
}
__device__ __forceinline__ void ld8(float* d, const float* p) {
    float4 u = ld4(p), v = ld4(p + 4);
    d[0] = u.x; d[1] = u.y; d[2] = u.z; d[3] = u.w;
    d[4] = v.x; d[5] = v.y; d[6] = v.z; d[7] = v.w;
}

// ---------------- CSR build ----------------

__global__ void hist_k(const int* __restrict__ edst, int* __restrict__ cnt, int E, int EN) {
    int i = blockIdx.x * 256 + threadIdx.x;
    if (i >= EN) return;
    int d = (i < E) ? edst[i] : (i - E);   // self-loop for i>=E
    atomicAdd(&cnt[d], 1);
}

__global__ __launch_bounds__(256)
void scanA_k(const int* __restrict__ cnt, int* __restrict__ rowptr,
             int* __restrict__ bsum, int n) {
    __shared__ int sh[256];
    int t = threadIdx.x;
    int i = blockIdx.x * 256 + t;
    int v = (i < n) ? cnt[i] : 0;
    sh[t] = v;
    __syncthreads();
#pragma unroll
    for (int off = 1; off < 256; off <<= 1) {
        int u = 0;
        if (t >= off) u = sh[t - off];
        __syncthreads();
        sh[t] += u;
        __syncthreads();
    }
    if (i < n) rowptr[i] = sh[t] - v;
    if (t == 255) bsum[blockIdx.x] = sh[255];
}

__global__ __launch_bounds__(256)
void scanB_k(int* __restrict__ bsum, int nb) {
    __shared__ int sh[256];
    int t = threadIdx.x;
    int v = (t < nb) ? bsum[t] : 0;
    sh[t] = v;
    __syncthreads();
#pragma unroll
    for (int off = 1; off < 256; off <<= 1) {
        int u = 0;
        if (t >= off) u = sh[t - off];
        __syncthreads();
        sh[t] += u;
        __syncthreads();
    }
    if (t < nb) bsum[t] = sh[t] - v;
}

__global__ __launch_bounds__(256)
void scanC_k(const int* __restrict__ cnt, const int* __restrict__ bsum,
             int* __restrict__ rowptr, int* __restrict__ cursor,
             float* __restrict__ dis, int n, int EN) {
    int i = blockIdx.x * 256 + threadIdx.x;
    if (i < n) {
        int r = rowptr[i] + bsum[blockIdx.x];
        rowptr[i] = r;
        cursor[i] = r;
        dis[i] = rsqrtf((float)cnt[i]);
    }
    if (i == 0) rowptr[n] = EN;
}

__global__ void scatter_k(const int* __restrict__ esrc, const int* __restrict__ edst,
                          int* __restrict__ cursor, int* __restrict__ colidx, int E, int EN) {
    int i = blockIdx.x * 256 + threadIdx.x;
    if (i >= EN) return;
    int s, d;
    if (i < E) { s = esrc[i]; d = edst[i]; }
    else       { s = i - E; d = s; }
    int pos = atomicAdd(&cursor[d], 1);
    colidx[pos] = s;
}

// ---------------- all-weights -> MFMA-fragment-order fp16 (one launch) ----------------
// Fragment order: off(ct,k32,lane,j) = ((ct*(K/32)+k32)*64 + lane)*8 + j, where
// lane=quad*16+m holds element (k = k32*32+quad*8+j, col = ct*16+m).
// Also computes the layer-0 algebraic folds:
//   Mg0 = gcn_in_w @ gcn_w[0]   (64x128, K=64 frags)  cg0 = gcn_in_b @ gcn_w[0]
//   Ma0 = gat_in_w @ gat_w[0]   (64x128)              ca0 = gat_in_b @ gat_w[0]
//   Da  = gat_in_w @ PD0        (64x16 tile)          oa  = gat_in_b @ PD0
// where PD0 is layer-0's projected attention tile (asrc cols 0..3, adst cols 8..11).

__device__ __forceinline__ float pd0_elem(const float* __restrict__ gat_w,
                                          const float* __restrict__ gat_asrc,
                                          const float* __restrict__ gat_adst,
                                          int t, int col) {
    // layer 0: hh=4, C=32
    float p = 0.f;
    if (col < 4) {
        const float* w = gat_w + (size_t)t * 128 + col * 32;
        const float* av = gat_asrc + col * 32;
        for (int c2 = 0; c2 < 32; ++c2) p += w[c2] * av[c2];
    } else if (col >= 8 && col < 12) {
        int hh2 = col - 8;
        const float* w = gat_w + (size_t)t * 128 + hh2 * 32;
        const float* av = gat_adst + hh2 * 32;
        for (int c2 = 0; c2 < 32; ++c2) p += w[c2] * av[c2];
    }
    return p;
}

__global__ void wtx_all_k(const float* __restrict__ gcn_in_w, const float* __restrict__ gcn_res_w,
                          const float* __restrict__ gat_in_w,
                          const float* __restrict__ gcn_w, const float* __restrict__ gat_w,
                          const float* __restrict__ gcn_c1w, const float* __restrict__ gat_c1w,
                          const float* __restrict__ gcn_c3w, const float* __restrict__ gat_c3w,
                          const float* __restrict__ fin_w,
                          const float* __restrict__ gcn_c2w, const float* __restrict__ gat_c2w,
                          const float* __restrict__ gat_asrc, const float* __restrict__ gat_adst,
                          const float* __restrict__ gcn_in_b, const float* __restrict__ gat_in_b,
                          __half* __restrict__ WTin, __half* __restrict__ WTg,
                          __half* __restrict__ WTa, __half* __restrict__ WTc1,
                          __half* __restrict__ WTc3, __half* __restrict__ WTfin,
                          __half* __restrict__ WTc2, __half* __restrict__ WTd,
                          __half* __restrict__ Mg0, __half* __restrict__ Ma0,
                          __half* __restrict__ Da, float* __restrict__ cg0,
                          float* __restrict__ ca0, float* __restrict__ oa) {
    int idx = blockIdx.x * 256 + threadIdx.x;
    const float* src;
    __half* dst;
    int K, M, o;
    if (idx < 24576) {                      // 3x (64x128) input mats
        int mi = idx >> 13; o = idx & 8191;
        src = mi == 0 ? gcn_in_w : (mi == 1 ? gcn_res_w : gat_in_w);
        dst = WTin + mi * 8192; K = 64; M = 128;
    } else if (idx < 73728) {               // 3x (128x128) gcn layer mats
        int r = idx - 24576; int mi = r >> 14; o = r & 16383;
        src = gcn_w + mi * 16384; dst = WTg + mi * 16384; K = 128; M = 128;
    } else if (idx < 122880) {              // 3x (128x128) gat layer mats
        int r = idx - 73728; int mi = r >> 14; o = r & 16383;
        src = gat_w + mi * 16384; dst = WTa + mi * 16384; K = 128; M = 128;
    } else if (idx < 139264) {              // 2x (128x64) c1 mats
        int r = idx - 122880; int mi = r >> 13; o = r & 8191;
        src = mi ? gat_c1w : gcn_c1w; dst = WTc1 + mi * 8192; K = 128; M = 64;
    } else if (idx < 147456) {              // 2x (32x128) c3 mats
        int r = idx - 139264; int mi = r >> 12; o = r & 4095;
        src = mi ? gat_c3w : gcn_c3w; dst = WTc3 + mi * 4096; K = 32; M = 128;
    } else if (idx < 155648) {              // fin (128x64)
        o = idx - 147456; src = fin_w; dst = WTfin; K = 128; M = 64;
    } else if (idx < 159744) {              // 2x (64x32) c2 mats
        int r = idx - 155648; int mi = r >> 11; o = r & 2047;
        src = mi ? gat_c2w : gcn_c2w; dst = WTc2 + mi * 2048; K = 64; M = 32;
    } else if (idx < 165888) {              // 3x (16x128) projected attention tiles
        int r = idx - 159744;
        int layer = r >> 11; o = r & 2047;
        int j = o & 7, lane = (o >> 3) & 63, k32 = o >> 9;
        int col = lane & 15, quad = lane >> 4;
        int k = k32 * 32 + quad * 8 + j;
        int hh = (layer < 2) ? 4 : 1;
        int C = 128 / hh;
        float v = 0.f;
        if (col < hh) {
            const float* w = gat_w + (size_t)(layer * 128 + k) * 128 + col * C;
            const float* av = gat_asrc + layer * 128 + col * C;
            for (int c2 = 0; c2 < C; ++c2) v += w[c2] * av[c2];
        } else if (col >= 8 && col < 8 + hh) {
            int hthis = col - 8;
            const float* w = gat_w + (size_t)(layer * 128 + k) * 128 + hthis * C;
            const float* av = gat_adst + layer * 128 + hthis * C;
            for (int c2 = 0; c2 < C; ++c2) v += w[c2] * av[c2];
        }
        WTd[(size_t)layer * 2048 + o] = (__half)v;
        return;
    } else if (idx < 183296) {              // Mg0 / Ma0 folded layer-0 mats (K=64 frags)
        int r = idx - 165888;
        bool isA = r >= 8192;
        o = r & 8191;
        int j = o & 7, lane = (o >> 3) & 63, rr = o >> 9;
        int ct = rr >> 1, k32 = rr & 1;
        int m = lane & 15, quad = lane >> 4;
        int k = k32 * 32 + quad * 8 + j;
        int col = ct * 16 + m;
        const float* inw = isA ? gat_in_w : gcn_in_w;
        const float* lw  = isA ? gat_w : gcn_w;   // layer 0
        float v = 0.f;
        for (int t = 0; t < 128; ++t) v += inw[k * 128 + t] * lw[(size_t)t * 128 + col];
        (isA ? Ma0 : Mg0)[o] = (__half)v;
        return;
    } else if (idx < 184320) {              // Da = gat_in_w @ PD0 (64x16 tile, K=64 frags)
        o = idx - 183296;
        int j = o & 7, lane = (o >> 3) & 63, k32 = o >> 9;
        int col = lane & 15, quad = lane >> 4;
        int k = k32 * 32 + quad * 8 + j;
        float v = 0.f;
        if (col < 4 || (col >= 8 && col < 12)) {
            for (int t = 0; t < 128; ++t)
                v += gat_in_w[k * 128 + t] * pd0_elem(gat_w, gat_asrc, gat_adst, t, col);
        }
        Da[o] = (__half)v;
        return;
    } else if (idx < 184448) {              // cg0 = gcn_in_b @ gcn_w0
        int col = idx - 184320;
        float v = 0.f;
        for (int t = 0; t < 128; ++t) v += gcn_in_b[t] * gcn_w[(size_t)t * 128 + col];
        cg0[col] = v;
        return;
    } else if (idx < 184576) {              // ca0 = gat_in_b @ gat_w0
        int col = idx - 184448;
        float v = 0.f;
        for (int t = 0; t < 128; ++t) v += gat_in_b[t] * gat_w[(size_t)t * 128 + col];
        ca0[col] = v;
        return;
    } else if (idx < 184592) {              // oa = gat_in_b @ PD0 (16 tile cols)
        int col = idx - 184576;
        float v = 0.f;
        if (col < 4 || (col >= 8 && col < 12)) {
            for (int t = 0; t < 128; ++t)
                v += gat_in_b[t] * pd0_elem(gat_w, gat_asrc, gat_adst, t, col);
        }
        oa[col] = v;
        return;
    } else return;
    // fragment-order decomposition
    int j = o & 7, lane = (o >> 3) & 63, r = o >> 9;
    int KD32 = K >> 5;
    int ct = r / KD32, k32 = r - ct * KD32;
    int m = lane & 15, quad = lane >> 4;
    int k = k32 * 32 + quad * 8 + j;
    int mcol = ct * 16 + m;
    dst[o] = (__half)src[k * M + mcol];
}

// ---------------- MFMA dense kernels ----------------

__device__ __forceinline__ f16x8 mk_af(const float* xr, int kb) {
    float4 v0 = ld4(xr + kb), v1 = ld4(xr + kb + 4);
    f16x8 af;
    af[0] = (_Float16)v0.x; af[1] = (_Float16)v0.y;
    af[2] = (_Float16)v0.z; af[3] = (_Float16)v0.w;
    af[4] = (_Float16)v1.x; af[5] = (_Float16)v1.y;
    af[6] = (_Float16)v1.z; af[7] = (_Float16)v1.w;
    return af;
}

// ---------------- layer-0 fused dual GEMM (x fp32 in, K=64 folded weights) ----------------
// gcn blocks: Y = (x@Mg0 + cg0)*dis, plus R = x@res_w + res_b.
// gat blocks: Y = x@Ma0 + ca0, attention dots via Da tile (+oa offsets).

__global__ __launch_bounds__(256)
void dual0_mfma_k(const float* __restrict__ X,
                  const __half* __restrict__ Mg0, const __half* __restrict__ Wres,
                  const float* __restrict__ resb,
                  const __half* __restrict__ Ma0, const __half* __restrict__ Da,
                  const float* __restrict__ cg0, const float* __restrict__ ca0,
                  const float* __restrict__ oa,
                  const float* __restrict__ dis,
                  __half* __restrict__ Yg, __half* __restrict__ Rout,
                  __half* __restrict__ Ya,
                  float* __restrict__ avp, float* __restrict__ bvp,
                  int hh, int n, int gper) {
    bool gat = blockIdx.x >= gper;
    int blk = gat ? blockIdx.x - gper : blockIdx.x;
    int wave = threadIdx.x >> 6, lane = threadIdx.x & 63;
    int m = lane & 15, quad = lane >> 4;
    int row0 = blk * 64 + wave * 16;
    int arow = min(row0 + m, n - 1);
    const float* xr = X + (size_t)arow * 64;
    f16x8 xf0 = mk_af(xr, quad * 8);
    f16x8 xf1 = mk_af(xr, 32 + quad * 8);
    int row = row0 + m;
    f32x4 acc[8];
    if (!gat) {
        // ---- Y0 ----
#pragma unroll
        for (int ct = 0; ct < 8; ++ct) acc[ct] = (f32x4){0.f, 0.f, 0.f, 0.f};
#pragma unroll
        for (int ct = 0; ct < 8; ++ct) {
            f16x8 b0 = *reinterpret_cast<const f16x8*>(Mg0 + ((ct * 2 + 0) << 9) + (lane << 3));
            f16x8 b1 = *reinterpret_cast<const f16x8*>(Mg0 + ((ct * 2 + 1) << 9) + (lane << 3));
            acc[ct] = __builtin_amdgcn_mfma_f32_16x16x32_f16(b0, xf0, acc[ct], 0, 0, 0);
            acc[ct] = __builtin_amdgcn_mfma_f32_16x16x32_f16(b1, xf1, acc[ct], 0, 0, 0);
        }
        if (row < n) {
            float dv = dis[row];
#pragma unroll
            for (int ct = 0; ct < 8; ++ct) {
                int col = ct * 16 + quad * 4;
                float4 cb = ld4(cg0 + col);
                H4u w;
                w.h[0] = (__half)((acc[ct][0] + cb.x) * dv);
                w.h[1] = (__half)((acc[ct][1] + cb.y) * dv);
                w.h[2] = (__half)((acc[ct][2] + cb.z) * dv);
                w.h[3] = (__half)((acc[ct][3] + cb.w) * dv);
                *reinterpret_cast<uint2*>(Yg + (size_t)row * 128 + col) = w.u2;
            }
        }
        // ---- R ----
#pragma unroll
        for (int ct = 0; ct < 8; ++ct) acc[ct] = (f32x4){0.f, 0.f, 0.f, 0.f};
#pragma unroll
        for (int ct = 0; ct < 8; ++ct) {
            f16x8 b0 = *reinterpret_cast<const f16x8*>(Wres + ((ct * 2 + 0) << 9) + (lane << 3));
            f16x8 b1 = *reinterpret_cast<const f16x8*>(Wres + ((ct * 2 + 1) << 9) + (lane << 3));
            acc[ct] = __builtin_amdgcn_mfma_f32_16x16x32_f16(b0, xf0, acc[ct], 0, 0, 0);
            acc[ct] = __builtin_amdgcn_mfma_f32_16x16x32_f16(b1, xf1, acc[ct], 0, 0, 0);
        }
        if (row < n) {
#pragma unroll
            for (int ct = 0; ct < 8; ++ct) {
                int col = ct * 16 + quad * 4;
                float4 cb = ld4(resb + col);
                H4u w;
                w.h[0] = (__half)(acc[ct][0] + cb.x);
                w.h[1] = (__half)(acc[ct][1] + cb.y);
                w.h[2] = (__half)(acc[ct][2] + cb.z);
                w.h[3] = (__half)(acc[ct][3] + cb.w);
                *reinterpret_cast<uint2*>(Rout + (size_t)row * 128 + col) = w.u2;
            }
        }
    } else {
        f32x4 accd = (f32x4){0.f, 0.f, 0.f, 0.f};
#pragma unroll
        for (int ct = 0; ct < 8; ++ct) acc[ct] = (f32x4){0.f, 0.f, 0.f, 0.f};
#pragma unroll
        for (int ct = 0; ct < 8; ++ct) {
            f16x8 b0 = *reinterpret_cast<const f16x8*>(Ma0 + ((ct * 2 + 0) << 9) + (lane << 3));
            f16x8 b1 = *reinterpret_cast<const f16x8*>(Ma0 + ((ct * 2 + 1) << 9) + (lane << 3));
            acc[ct] = __builtin_amdgcn_mfma_f32_16x16x32_f16(b0, xf0, acc[ct], 0, 0, 0);
            acc[ct] = __builtin_amdgcn_mfma_f32_16x16x32_f16(b1, xf1, acc[ct], 0, 0, 0);
        }
        {
            f16x8 d0 = *reinterpret_cast<const f16x8*>(Da + (0 << 9) + (lane << 3));
            f16x8 d1 = *reinterpret_cast<const f16x8*>(Da + (1 << 9) + (lane << 3));
            accd = __builtin_amdgcn_mfma_f32_16x16x32_f16(d0, xf0, accd, 0, 0, 0);
            accd = __builtin_amdgcn_mfma_f32_16x16x32_f16(d1, xf1, accd, 0, 0, 0);
        }
        if (row < n) {
#pragma unroll
            for (int ct = 0; ct < 8; ++ct) {
                int col = ct * 16 + quad * 4;
                float4 cb = ld4(ca0 + col);
                H4u w;
                w.h[0] = (__half)(acc[ct][0] + cb.x);
                w.h[1] = (__half)(acc[ct][1] + cb.y);
                w.h[2] = (__half)(acc[ct][2] + cb.z);
                w.h[3] = (__half)(acc[ct][3] + cb.w);
                *reinterpret_cast<uint2*>(Ya + (size_t)row * 128 + col) = w.u2;
            }
            if (quad == 0) {
#pragma unroll
                for (int reg = 0; reg < 4; ++reg)
                    if (reg < hh) avp[row * hh + reg] = accd[reg] + oa[reg];
            } else if (quad == 2) {
#pragma unroll
                for (int reg = 0; reg < 4; ++reg)
                    if (reg < hh) bvp[row * hh + reg] = accd[reg] + oa[8 + reg];
            }
        }
    }
}

// ---------------- per-layer pair GEMM via MFMA (fp16 act, fragment weights) ----------------
// gcn blocks: Y = (X@W)*dis. gat blocks: Y = X@W + attention dots via 9th tile.

__global__ __launch_bounds__(256)
void dual128_mfma_k(const __half* __restrict__ Xg, const __half* __restrict__ WTg,
                    __half* __restrict__ Yg,
                    const __half* __restrict__ Xa, const __half* __restrict__ WTa,
                    __half* __restrict__ Ya,
                    const float* __restrict__ dis,
                    const __half* __restrict__ WTd,
                    float* __restrict__ avp, float* __restrict__ bvp,
                    int hh, int n, int gper) {
    bool gat = blockIdx.x >= gper;
    int blk = gat ? blockIdx.x - gper : blockIdx.x;
    const __half* X = gat ? Xa : Xg;
    const __half* WT = gat ? WTa : WTg;
    __half* Y = gat ? Ya : Yg;
    int wave = threadIdx.x >> 6;
    int lane = threadIdx.x & 63;
    int m = lane & 15, quad = lane >> 4;
    int row0 = blk * 64 + wave * 16;
    int arow = min(row0 + m, n - 1);
    const __half* xr = X + (size_t)arow * 128;
    f32x4 acc[8];
#pragma unroll
    for (int ct = 0; ct < 8; ++ct) acc[ct] = (f32x4){0.f, 0.f, 0.f, 0.f};
    int row = row0 + m;
    if (!gat) {
#pragma unroll
        for (int k32 = 0; k32 < 4; ++k32) {
            int kb = k32 * 32 + quad * 8;
            f16x8 af = *reinterpret_cast<const f16x8*>(xr + kb);
#pragma unroll
            for (int ct = 0; ct < 8; ++ct) {
                f16x8 bf = *reinterpret_cast<const f16x8*>(WT + ((ct * 4 + k32) << 9) + (lane << 3));
                acc[ct] = __builtin_amdgcn_mfma_f32_16x16x32_f16(bf, af, acc[ct], 0, 0, 0);
            }
        }
        if (row < n) {
            float dv = dis[row];
#pragma unroll
            for (int ct = 0; ct < 8; ++ct) {
                int col = ct * 16 + quad * 4;
                H4u w;
                w.h[0] = (__half)(acc[ct][0] * dv);
                w.h[1] = (__half)(acc[ct][1] * dv);
                w.h[2] = (__half)(acc[ct][2] * dv);
                w.h[3] = (__half)(acc[ct][3] * dv);
                *reinterpret_cast<uint2*>(Y + (size_t)row * 128 + col) = w.u2;
            }
        }
    } else {
        f32x4 accd = (f32x4){0.f, 0.f, 0.f, 0.f};
#pragma unroll
        for (int k32 = 0; k32 < 4; ++k32) {
            int kb = k32 * 32 + quad * 8;
            f16x8 af = *reinterpret_cast<const f16x8*>(xr + kb);
#pragma unroll
            for (int ct = 0; ct < 8; ++ct) {
                f16x8 bf = *reinterpret_cast<const f16x8*>(WT + ((ct * 4 + k32) << 9) + (lane << 3));
                acc[ct] = __builtin_amdgcn_mfma_f32_16x16x32_f16(bf, af, acc[ct], 0, 0, 0);
            }
            f16x8 bd = *reinterpret_cast<const f16x8*>(WTd + (k32 << 9) + (lane << 3));
            accd = __builtin_amdgcn_mfma_f32_16x16x32_f16(bd, af, accd, 0, 0, 0);
        }
        if (row < n) {
#pragma unroll
            for (int ct = 0; ct < 8; ++ct) {
                int col = ct * 16 + quad * 4;
                H4u w;
                w.h[0] = (__half)acc[ct][0];
                w.h[1] = (__half)acc[ct][1];
                w.h[2] = (__half)acc[ct][2];
                w.h[3] = (__half)acc[ct][3];
                *reinterpret_cast<uint2*>(Y + (size_t)row * 128 + col) = w.u2;
            }
            if (quad == 0) {
#pragma unroll
                for (int reg = 0; reg < 4; ++reg)
                    if (reg < hh) avp[row * hh + reg] = accd[reg];
            } else if (quad == 2) {
#pragma unroll
                for (int reg = 0; reg < 4; ++reg)
                    if (reg < hh) bvp[row * hh + reg] = accd[reg];
            }
        }
    }
}

// ---------------- fused sparse aggregation (proven 52us structure) ----------------
// 16 lanes/node, 8 cols (16B fp16) per lane per table; colidx + avp software-
// pipelined; ALL edges via fully-masked 4-edge groups (no serial remainder).

__global__ __launch_bounds__(256)
void fused_gather_k(const int* __restrict__ rowptr, const int* __restrict__ colidx,
                    const float* __restrict__ dis,
                    const __half* __restrict__ Tg, const float* __restrict__ gbias,
                    const float* __restrict__ gbng, const float* __restrict__ gbnb,
                    const __half* __restrict__ res, __half* __restrict__ Yg,
                    const __half* __restrict__ Ta, const float* __restrict__ avp,
                    const float* __restrict__ bvp, const float* __restrict__ abias,
                    const float* __restrict__ abng, const float* __restrict__ abnb,
                    const float* __restrict__ fimp, __half* __restrict__ Ya,
                    int n, int hh, int log2C) {
    int idx = blockIdx.x * 256 + threadIdx.x;
    int i = idx >> 4;
    if (i >= n) return;
    int c = (idx & 15) * 8;
    int h = c >> log2C;
    float ad = bvp[i * hh + h];
    int p0 = rowptr[i], p1 = rowptr[i + 1];
    float g[8], a[8];
#pragma unroll
    for (int t = 0; t < 8; ++t) { g[t] = 0.f; a[t] = 0.f; }
    float m = -3.0e38f, s = 0.f;

    int ng = (p1 - p0 + 3) >> 2;            // fully-masked 4-edge groups
    int p = p0;
    int sx[4]; float av[4], vm[4];
#pragma unroll
    for (int j = 0; j < 4; ++j) {
        int q = p0 + j;
        vm[j] = (q < p1) ? 1.f : 0.f;
        sx[j] = colidx[min(q, p1 - 1)];
    }
#pragma unroll
    for (int j = 0; j < 4; ++j) av[j] = avp[sx[j] * hh + h];

    for (int gi = 0; gi < ng; ++gi) {
        // issue the 8 long-latency gathers first
        uint4 qg[4], qa[4];
#pragma unroll
        for (int j = 0; j < 4; ++j)
            qg[j] = *reinterpret_cast<const uint4*>(Tg + (size_t)sx[j] * 128 + c);
#pragma unroll
        for (int j = 0; j < 4; ++j)
            qa[j] = *reinterpret_cast<const uint4*>(Ta + (size_t)sx[j] * 128 + c);
        // prefetch next group's indices + attention scores while gathers fly
        int pn = p + 4;
        int sn[4]; float avn[4], vmn[4];
#pragma unroll
        for (int j = 0; j < 4; ++j) {
            int q = pn + j;
            vmn[j] = (q < p1) ? 1.f : 0.f;
            sn[j] = colidx[min(max(q, p0), p1 - 1)];
        }
#pragma unroll
        for (int j = 0; j < 4; ++j) avn[j] = avp[sn[j] * hh + h];
        // softmax scalars (v_exp_f32); invalid slots -> e=-3e38 -> w=0
        float e0 = vm[0] > 0.f ? leaky02(av[0] + ad) : -3.0e38f;
        float e1 = vm[1] > 0.f ? leaky02(av[1] + ad) : -3.0e38f;
        float e2 = vm[2] > 0.f ? leaky02(av[2] + ad) : -3.0e38f;
        float e3 = vm[3] > 0.f ? leaky02(av[3] + ad) : -3.0e38f;
        float mc = fmaxf(fmaxf(e0, e1), fmaxf(e2, e3));
        float mn = fmaxf(m, mc);
        float scale = __expf(m - mn);
        float w0 = __expf(e0 - mn), w1 = __expf(e1 - mn);
        float w2 = __expf(e2 - mn), w3 = __expf(e3 - mn);
        s = s * scale + (w0 + w1 + w2 + w3);
        m = mn;
        // GCN accumulate, masked by vm (v_fma_mix)
        {
            H8u k0, k1, k2, k3;
            k0.u4 = qg[0]; k1.u4 = qg[1]; k2.u4 = qg[2]; k3.u4 = qg[3];
#pragma unroll
            for (int t = 0; t < 8; ++t) {
                float v = g[t];
                v = fmaf(__half2float(k0.h[t]), vm[0], v);
                v = fmaf(__half2float(k1.h[t]), vm[1], v);
                v = fmaf(__half2float(k2.h[t]), vm[2], v);
                v = fmaf(__half2float(k3.h[t]), vm[3], v);
                g[t] = v;
            }
        }
        // GAT online accumulate
        {
            H8u k0, k1, k2, k3;
            k0.u4 = qa[0]; k1.u4 = qa[1]; k2.u4 = qa[2]; k3.u4 = qa[3];
#pragma unroll
            for (int t = 0; t < 8; ++t) {
                float v = a[t] * scale;
                v = fmaf(__half2float(k0.h[t]), w0, v);
                v = fmaf(__half2float(k1.h[t]), w1, v);
                v = fmaf(__half2float(k2.h[t]), w2, v);
                v = fmaf(__half2float(k3.h[t]), w3, v);
                a[t] = v;
            }
        }
        p = pn;
#pragma unroll
        for (int j = 0; j < 4; ++j) { sx[j] = sn[j]; av[j] = avn[j]; vm[j] = vmn[j]; }
    }

    // ---- GCN epilogue (fp16 out) ----
    {
        float di = dis[i];
        float bb[8], gg[8], nb[8];
        ld8(bb, gbias + c); ld8(gg, gbng + c); ld8(nb, gbnb + c);
        float o[8];
#pragma unroll
        for (int t = 0; t < 8; ++t) {
            float v = g[t] * di + bb[t];
            o[t] = fmaxf(v * (gg[t] * RSQ_BN) + nb[t], 0.f);
        }
        if (res) {
            H8u rr;
            rr.u4 = *reinterpret_cast<const uint4*>(res + (size_t)i * 128 + c);
#pragma unroll
            for (int t = 0; t < 8; ++t) o[t] += __half2float(rr.h[t]);
        }
        H8u w;
#pragma unroll
        for (int t = 0; t < 8; ++t) w.h[t] = (__half)o[t];
        *reinterpret_cast<uint4*>(Yg + (size_t)i * 128 + c) = w.u4;
    }
    // ---- GAT epilogue (fp16 out) ----
    {
        float si = 1.f / (s + 1e-16f);
        float bb[8], gg[8], nb[8];
        ld8(bb, abias + c); ld8(gg, abng + c); ld8(nb, abnb + c);
        float o[8];
#pragma unroll
        for (int t = 0; t < 8; ++t) {
            float v = a[t] * si + bb[t];
            v = v * (gg[t] * RSQ_BN) + nb[t];
            o[t] = v > 0.f ? v : expm1f(v);
        }
        if (fimp) {
            float ff[8]; ld8(ff, fimp + c);
#pragma unroll
            for (int t = 0; t < 8; ++t) o[t] *= ff[t];
        }
        H8u w;
#pragma unroll
        for (int t = 0; t < 8; ++t) w.h[t] = (__half)o[t];
        *reinterpret_cast<uint4*>(Ya + (size_t)i * 128 + c) = w.u4;
    }
}

// ---------------- fused MLP tail: c1 -> c2 -> c3 -> blend -> fin -> bn -> fin2 ----------------
// One block = 64 rows, 4 waves x 16 rows. Intermediates in LDS; fragment weights.

__global__ __launch_bounds__(256)
void fused_tail_k(const __half* __restrict__ Xg, const __half* __restrict__ Xa,
                  const __half* __restrict__ WTc1,
                  const float* __restrict__ c1bg, const float* __restrict__ c1ba,
                  const float* __restrict__ cbng, const float* __restrict__ cbnb,
                  const __half* __restrict__ WTc2,
                  const float* __restrict__ c2bg, const float* __restrict__ c2ba,
                  const __half* __restrict__ WTc3,
                  const float* __restrict__ c3bg, const float* __restrict__ c3ba,
                  const __half* __restrict__ WTfin, const float* __restrict__ finb,
                  const float* __restrict__ fbng, const float* __restrict__ fbnb,
                  const float* __restrict__ w2, const float* __restrict__ b2,
                  float* __restrict__ out, int n) {
    __shared__ alignas(16) __half h1s[2][64][88];
    __shared__ alignas(16) __half h2s[2][64][56];
    __shared__ alignas(16) __half Fs[64][152];
    int wave = threadIdx.x >> 6, lane = threadIdx.x & 63;
    int m = lane & 15, quad = lane >> 4;
    int row0 = blockIdx.x * 64 + wave * 16;
    int lr0 = wave * 16;
    int arow = min(row0 + m, n - 1);

    // ---- S1: X @ c1 (K=128,M=64), relu [+bn for gat] -> h1 ----
#pragma unroll
    for (int br = 0; br < 2; ++br) {
        const __half* xr = (br ? Xa : Xg) + (size_t)arow * 128;
        const __half* WT = WTc1 + br * 8192;
        f32x4 acc[4];
#pragma unroll
        for (int ct = 0; ct < 4; ++ct) acc[ct] = (f32x4){0.f, 0.f, 0.f, 0.f};
#pragma unroll
        for (int k32 = 0; k32 < 4; ++k32) {
            int kb = k32 * 32 + quad * 8;
            f16x8 af = *reinterpret_cast<const f16x8*>(xr + kb);
#pragma unroll
            for (int ct = 0; ct < 4; ++ct) {
                f16x8 bf = *reinterpret_cast<const f16x8*>(WT + ((ct * 4 + k32) << 9) + (lane << 3));
                acc[ct] = __builtin_amdgcn_mfma_f32_16x16x32_f16(af, bf, acc[ct], 0, 0, 0);
            }
        }
        const float* bi = br ? c1ba : c1bg;
#pragma unroll
        for (int ct = 0; ct < 4; ++ct) {
            int col = ct * 16 + m;
            float cb = bi[col];
            float cg = br ? cbng[col] * RSQ_BN : 1.f;
            float cbb = br ? cbnb[col] : 0.f;
#pragma unroll
            for (int reg = 0; reg < 4; ++reg) {
                float v = fmaxf(acc[ct][reg] + cb, 0.f) * cg + cbb;
                h1s[br][lr0 + quad * 4 + reg][col] = (__half)v;
            }
        }
    }
    __syncthreads();
    // ---- S2: h1 @ c2 (K=64,M=32), relu -> h2 ----
#pragma unroll
    for (int br = 0; br < 2; ++br) {
        f32x4 acc[2];
        acc[0] = (f32x4){0.f, 0.f, 0.f, 0.f};
        acc[1] = (f32x4){0.f, 0.f, 0.f, 0.f};
        const __half* WT = WTc2 + br * 2048;
#pragma unroll
        for (int k32 = 0; k32 < 2; ++k32) {
            int kb = k32 * 32 + quad * 8;
            f16x8 af = *reinterpret_cast<const f16x8*>(&h1s[br][lr0 + m][kb]);
#pragma unroll
            for (int ct = 0; ct < 2; ++ct) {
                f16x8 bf = *reinterpret_cast<const f16x8*>(WT + ((ct * 2 + k32) << 9) + (lane << 3));
                acc[ct] = __builtin_amdgcn_mfma_f32_16x16x32_f16(af, bf, acc[ct], 0, 0, 0);
            }
        }
        const float* bi = br ? c2ba : c2bg;
#pragma unroll
        for (int ct = 0; ct < 2; ++ct) {
            int col = ct * 16 + m;
            float cb = bi[col];
#pragma unroll
            for (int reg = 0; reg < 4; ++reg) {
                float v = fmaxf(acc[ct][reg] + cb, 0.f);
                h2s[br][lr0 + quad * 4 + reg][col] = (__half)v;
            }
        }
    }
    __syncthreads();
    // ---- S3: h2 @ c3 (K=32,M=128), both branches, blend -> F ----
    {
        f32x4 ag[8], aa[8];
#pragma unroll
        for (int ct = 0; ct < 8; ++ct) {
            ag[ct] = (f32x4){0.f, 0.f, 0.f, 0.f};
            aa[ct] = (f32x4){0.f, 0.f, 0.f, 0.f};
        }
        int kb = quad * 8;
        f16x8 afg = *reinterpret_cast<const f16x8*>(&h2s[0][lr0 + m][kb]);
        f16x8 afa = *reinterpret_cast<const f16x8*>(&h2s[1][lr0 + m][kb]);
#pragma unroll
        for (int ct = 0; ct < 8; ++ct) {
            f16x8 bfg = *reinterpret_cast<const f16x8*>(WTc3 + (ct << 9) + (lane << 3));
            f16x8 bfa = *reinterpret_cast<const f16x8*>(WTc3 + 4096 + (ct << 9) + (lane << 3));
            ag[ct] = __builtin_amdgcn_mfma_f32_16x16x32_f16(afg, bfg, ag[ct], 0, 0, 0);
            aa[ct] = __builtin_amdgcn_mfma_f32_16x16x32_f16(afa, bfa, aa[ct], 0, 0, 0);
        }
#pragma unroll
        for (int ct = 0; ct < 8; ++ct) {
            int col = ct * 16 + m;
            float cb = 0.6f * c3bg[col] + 0.4f * c3ba[col];
#pragma unroll
            for (int reg = 0; reg < 4; ++reg) {
                float v = 0.6f * ag[ct][reg] + 0.4f * aa[ct][reg] + cb;
                Fs[lr0 + quad * 4 + reg][col] = (__half)v;
            }
        }
    }
    __syncthreads();
    // ---- S4: F @ fin (K=128,M=64), relu, bn, @fin2 -> out[n,2] ----
    {
        f32x4 acc[4];
#pragma unroll
        for (int ct = 0; ct < 4; ++ct) acc[ct] = (f32x4){0.f, 0.f, 0.f, 0.f};
#pragma unroll
        for (int k32 = 0; k32 < 4; ++k32) {
            int kb = k32 * 32 + quad * 8;
            f16x8 af = *reinterpret_cast<const f16x8*>(&Fs[lr0 + m][kb]);
#pragma unroll
            for (int ct = 0; ct < 4; ++ct) {
                f16x8 bf = *reinterpret_cast<const f16x8*>(WTfin + ((ct * 4 + k32) << 9) + (lane << 3));
                acc[ct] = __builtin_amdgcn_mfma_f32_16x16x32_f16(af, bf, acc[ct], 0, 0, 0);
            }
        }
        float p0[4] = {0.f, 0.f, 0.f, 0.f}, p1[4] = {0.f, 0.f, 0.f, 0.f};
#pragma unroll
        for (int ct = 0; ct < 4; ++ct) {
            int col = ct * 16 + m;
            float cb = finb[col];
            float cg = fbng[col] * RSQ_BN;
            float cbb = fbnb[col];
            float w20 = w2[2 * col], w21 = w2[2 * col + 1];
#pragma unroll
            for (int reg = 0; reg < 4; ++reg) {
                float v = fmaxf(acc[ct][reg] + cb, 0.f) * cg + cbb;
                p0[reg] += v * w20;
                p1[reg] += v * w21;
            }
        }
        for (int off = 1; off < 16; off <<= 1) {
#pragma unroll
            for (int reg = 0; reg < 4; ++reg) {
                p0[reg] += __shfl_xor(p0[reg], off);
                p1[reg] += __shfl_xor(p1[reg], off);
            }
        }
        if (m == 0) {
#pragma unroll
            for (int reg = 0; reg < 4; ++reg) {
                int row = row0 + quad * 4 + reg;
                if (row < n) {
                    out[row * 2] = p0[reg] + b2[0];
                    out[row * 2 + 1] = p1[reg] + b2[1];
                }
            }
        }
    }
}

// ---------------- host orchestration ----------------

static inline int cdiv(int a, int b) { return (a + b - 1) / b; }

extern "C" void kernel_launch(void* const* d_in, const int* in_sizes, int n_in,
                              void* d_out, int out_size, void* d_ws, size_t ws_size,
                              hipStream_t stream) {
    const float* x       = (const float*)d_in[0];
    const int*   ei      = (const int*)d_in[1];
    const float* gcn_in_w = (const float*)d_in[2];
    const float* gcn_in_b = (const float*)d_in[3];
    const float* gcn_res_w = (const float*)d_in[4];
    const float* gcn_res_b = (const float*)d_in[5];
    const float* gcn_w   = (const float*)d_in[6];
    const float* gcn_b   = (const float*)d_in[7];
    const float* gcn_bn_g = (const float*)d_in[8];
    const float* gcn_bn_b = (const float*)d_in[9];
    const float* gcn_c1w = (const float*)d_in[10];
    const float* gcn_c1b = (const float*)d_in[11];
    const float* gcn_c2w = (const float*)d_in[12];
    const float* gcn_c2b = (const float*)d_in[13];
    const float* gcn_c3w = (const float*)d_in[14];
    const float* gcn_c3b = (const float*)d_in[15];
    const float* gat_in_w = (const float*)d_in[16];
    const float* gat_in_b = (const float*)d_in[17];
    const float* gat_w   = (const float*)d_in[18];
    const float* gat_asrc = (const float*)d_in[19];
    const float* gat_adst = (const float*)d_in[20];
    const float* gat_b   = (const float*)d_in[21];
    const float* gat_bn_g = (const float*)d_in[22];
    const float* gat_bn_b = (const float*)d_in[23];
    const float* feat_imp = (const float*)d_in[24];
    const float* gat_c1w = (const float*)d_in[25];
    const float* gat_c1b = (const float*)d_in[26];
    const float* gat_cbn_g = (const float*)d_in[27];
    const float* gat_cbn_b = (const float*)d_in[28];
    const float* gat_c2w = (const float*)d_in[29];
    const float* gat_c2b = (const float*)d_in[30];
    const float* gat_c3w = (const float*)d_in[31];
    const float* gat_c3b = (const float*)d_in[32];
    const float* fin_w   = (const float*)d_in[33];
    const float* fin_b   = (const float*)d_in[34];
    const float* fin_bn_g = (const float*)d_in[35];
    const float* fin_bn_b = (const float*)d_in[36];
    const float* fin2_w  = (const float*)d_in[37];
    const float* fin2_b  = (const float*)d_in[38];

    const int N = in_sizes[0] / 64;
    const int E = in_sizes[1] / 2;
    const int EN = E + N;
    const int* esrc = ei;
    const int* edst = ei + E;

    // workspace carve (256B aligned)
    char* wp = (char*)d_ws;
    auto alloc = [&](size_t bytes) -> void* {
        void* p = (void*)wp;
        wp += (bytes + 255) & ~(size_t)255;
        return p;
    };
    int* cnt    = (int*)alloc((size_t)N * 4);
    int* rowptr = (int*)alloc((size_t)(N + 1) * 4);
    int* cursor = (int*)alloc((size_t)N * 4);
    int* bsum   = (int*)alloc((size_t)256 * 4);
    int* colidx = (int*)alloc((size_t)EN * 4);
    float* dis  = (float*)alloc((size_t)N * 4);
    __half* A   = (__half*)alloc((size_t)N * 128 * 2);   // gcn ping (fp16)
    __half* B   = (__half*)alloc((size_t)N * 128 * 2);   // gcn pong
    __half* G   = (__half*)alloc((size_t)N * 128 * 2);   // gat ping
    __half* H   = (__half*)alloc((size_t)N * 128 * 2);   // gat pong
    __half* R   = (__half*)alloc((size_t)N * 128 * 2);   // gcn residual
    __half* Th1 = (__half*)alloc((size_t)N * 128 * 2);   // gcn fp16 gather table
    __half* Th2 = (__half*)alloc((size_t)N * 128 * 2);   // gat fp16 gather table
    float* avv  = (float*)alloc((size_t)N * 4 * 4);
    float* bvv  = (float*)alloc((size_t)N * 4 * 4);
    __half* WTin = (__half*)alloc((size_t)3 * 8192 * 2);
    __half* WTg  = (__half*)alloc((size_t)3 * 16384 * 2);
    __half* WTa  = (__half*)alloc((size_t)3 * 16384 * 2);
    __half* WTc1 = (__half*)alloc((size_t)2 * 8192 * 2);
    __half* WTc3 = (__half*)alloc((size_t)2 * 4096 * 2);
    __half* WTfin = (__half*)alloc((size_t)8192 * 2);
    __half* WTc2 = (__half*)alloc((size_t)2 * 2048 * 2);
    __half* WTd  = (__half*)alloc((size_t)3 * 2048 * 2);
    __half* Mg0  = (__half*)alloc((size_t)8192 * 2);
    __half* Ma0  = (__half*)alloc((size_t)8192 * 2);
    __half* Da   = (__half*)alloc((size_t)1024 * 2);
    float* cg0   = (float*)alloc((size_t)128 * 4);
    float* ca0   = (float*)alloc((size_t)128 * 4);
    float* oa    = (float*)alloc((size_t)16 * 4);

    // ---- CSR build + all-weight fragment transpose + layer-0 folds ----
    const int nScanB = cdiv(N, 256);
    hipMemsetAsync(cnt, 0, (size_t)N * 4, stream);
    hist_k<<<cdiv(EN, 256), 256, 0, stream>>>(edst, cnt, E, EN);
    scanA_k<<<nScanB, 256, 0, stream>>>(cnt, rowptr, bsum, N);
    scanB_k<<<1, 256, 0, stream>>>(bsum, nScanB);
    scanC_k<<<nScanB, 256, 0, stream>>>(cnt, bsum, rowptr, cursor, dis, N, EN);
    scatter_k<<<cdiv(EN, 256), 256, 0, stream>>>(esrc, edst, cursor, colidx, E, EN);
    wtx_all_k<<<721, 256, 0, stream>>>(gcn_in_w, gcn_res_w, gat_in_w, gcn_w, gat_w,
                                       gcn_c1w, gat_c1w, gcn_c3w, gat_c3w, fin_w,
                                       gcn_c2w, gat_c2w, gat_asrc, gat_adst,
                                       gcn_in_b, gat_in_b,
                                       WTin, WTg, WTa, WTc1, WTc3, WTfin, WTc2, WTd,
                                       Mg0, Ma0, Da, cg0, ca0, oa);

    const int g64r = cdiv(N, 64);    // mfma kernels: 64 rows/block
    const int gG   = cdiv(N, 16);    // gather: 16 nodes/block

    // ---- layer 0: folded input+conv GEMM (also produces R) ----
    dual0_mfma_k<<<2 * g64r, 256, 0, stream>>>(x, Mg0, WTin + 8192, gcn_res_b,
                                               Ma0, Da, cg0, ca0, oa, dis,
                                               Th1, R, Th2, avv, bvv, 4, N, g64r);
    fused_gather_k<<<gG, 256, 0, stream>>>(rowptr, colidx, dis,
                                           Th1, gcn_b, gcn_bn_g, gcn_bn_b, nullptr, A,
                                           Th2, avv, bvv, gat_b, gat_bn_g, gat_bn_b,
                                           nullptr, G, N, 4, 5);
    // ---- layer 1 ----
    dual128_mfma_k<<<2 * g64r, 256, 0, stream>>>(A, WTg + 16384, Th1,
                                                 G, WTa + 16384, Th2, dis,
                                                 WTd + 2048, avv, bvv, 4, N, g64r);
    fused_gather_k<<<gG, 256, 0, stream>>>(rowptr, colidx, dis,
                                           Th1, gcn_b + 128, gcn_bn_g + 128, gcn_bn_b + 128,
                                           R, B,
                                           Th2, avv, bvv, gat_b + 128, gat_bn_g + 128,
                                           gat_bn_b + 128, nullptr, H, N, 4, 5);
    // ---- layer 2 ----
    dual128_mfma_k<<<2 * g64r, 256, 0, stream>>>(B, WTg + 32768, Th1,
                                                 H, WTa + 32768, Th2, dis,
                                                 WTd + 4096, avv, bvv, 1, N, g64r);
    fused_gather_k<<<gG, 256, 0, stream>>>(rowptr, colidx, dis,
                                           Th1, gcn_b + 256, gcn_bn_g + 256, gcn_bn_b + 256,
                                           nullptr, A,
                                           Th2, avv, bvv, gat_b + 256, gat_bn_g + 256,
                                           gat_bn_b + 256, feat_imp, G, N, 1, 7);

    // ---- fused MLP tail: c1/c2/c3/blend/fin/fin2 in one kernel ----
    fused_tail_k<<<g64r, 256, 0, stream>>>(A, G,
                                           WTc1, gcn_c1b, gat_c1b, gat_cbn_g, gat_cbn_b,
                                           WTc2, gcn_c2b, gat_c2b,
                                           WTc3, gcn_c3b, gat_c3b,
                                           WTfin, fin_b, fin_bn_g, fin_bn_b,
                                           fin2_w, fin2_b, (float*)d_out, N);
}